// Round 1
// 587.273 us; speedup vs baseline: 1.2869x; 1.2869x over previous
//
#include <hip/hip_runtime.h>
#include <hip/hip_bf16.h>
#include <math.h>

typedef __hip_bfloat16 bf16;

#define HB 8
#define HH 56
#define WWD 56
#define DD 256
#define NHEAD 8
#define KDIM 32
#define FFND 1024
#define NPIX (HB*HH*WWD)             /* 25088 */
#define SCALE_K 0.17677669529663687f /* 32^-0.5 */

typedef __attribute__((ext_vector_type(8))) short short8;   // 8 bf16 (4 VGPRs)
typedef __attribute__((ext_vector_type(4))) float f32x4;

__device__ inline float toF(float x){ return x; }
__device__ inline float toF(bf16 x){ return __bfloat162float(x); }

__device__ inline float bfu_to_f(unsigned short u){
    union { float f; unsigned u32; } cv; cv.u32 = (unsigned)u << 16; return cv.f;
}

__device__ inline unsigned short f2bu(float f){
    union { bf16 b; unsigned short u; } cv; cv.b = __float2bfloat16(f); return cv.u;
}
__device__ inline unsigned pk2(float a, float b){
    return (unsigned)f2bu(a) | ((unsigned)f2bu(b) << 16);
}

// ---- vectorized depthwise conv (SAME, zero pad), optional +input.
// One thread owns VEC contiguous channels (8 bf16 via short8 / 4 fp32 via float4).
// PPB pixels per 256-thread block; pixels adjacent in w -> 1KB contiguous per wave tap.
template<int KS, typename T, bool ADD>
__global__ __launch_bounds__(256) void dwconv_vec_kernel(
    const T* __restrict__ in, const float* __restrict__ wt, int wst,
    const float* __restrict__ bias, T* __restrict__ out)
{
    constexpr int C   = 256;
    constexpr int VEC = (sizeof(T) == 2) ? 8 : 4;
    constexpr int CG  = C / VEC;          // 32 (bf16) or 64 (fp32)
    constexpr int PPB = 256 / CG;         // 8 (bf16) or 4 (fp32)
    constexpr int P   = KS / 2;

    const int tid = threadIdx.x;
    const int cg  = tid % CG;
    const int pl  = tid / CG;
    const int p   = blockIdx.x * PPB + pl;
    const int w   = p % WWD;
    const int h   = (p / WWD) % HH;
    const int b   = p / (WWD * HH);
    const int c0  = cg * VEC;

    float acc[VEC];
    {
        const float4 b0 = *(const float4*)(bias + c0);
        acc[0] = b0.x; acc[1] = b0.y; acc[2] = b0.z; acc[3] = b0.w;
        if constexpr (VEC == 8) {
            const float4 b1 = *(const float4*)(bias + c0 + 4);
            acc[4] = b1.x; acc[5] = b1.y; acc[6] = b1.z; acc[7] = b1.w;
        }
    }

    #pragma unroll
    for (int ky = 0; ky < KS; ky++) {
        const int hh = h + ky - P;
        if (hh < 0 || hh >= HH) continue;
        #pragma unroll
        for (int kx = 0; kx < KS; kx++) {
            const int ww = w + kx - P;
            if (ww < 0 || ww >= WWD) continue;
            const float* wp = wt + (size_t)(ky*KS + kx) * wst + c0;
            float wv[VEC];
            {
                const float4 w0 = *(const float4*)(wp);
                wv[0] = w0.x; wv[1] = w0.y; wv[2] = w0.z; wv[3] = w0.w;
                if constexpr (VEC == 8) {
                    const float4 w1 = *(const float4*)(wp + 4);
                    wv[4] = w1.x; wv[5] = w1.y; wv[6] = w1.z; wv[7] = w1.w;
                }
            }
            const T* src = in + ((size_t)((b*HH + hh)*WWD + ww))*C + c0;
            if constexpr (sizeof(T) == 2) {
                short8 vv = *(const short8*)src;
                #pragma unroll
                for (int j = 0; j < VEC; j++)
                    acc[j] += bfu_to_f((unsigned short)vv[j]) * wv[j];
            } else {
                const float4 f0 = *(const float4*)src;
                acc[0] += f0.x * wv[0]; acc[1] += f0.y * wv[1];
                acc[2] += f0.z * wv[2]; acc[3] += f0.w * wv[3];
            }
        }
    }

    const size_t obase = (size_t)p*C + c0;
    if constexpr (ADD) {
        const T* ip = in + obase;
        if constexpr (sizeof(T) == 2) {
            short8 vv = *(const short8*)ip;
            #pragma unroll
            for (int j = 0; j < VEC; j++) acc[j] += bfu_to_f((unsigned short)vv[j]);
        } else {
            const float4 f0 = *(const float4*)ip;
            acc[0] += f0.x; acc[1] += f0.y; acc[2] += f0.z; acc[3] += f0.w;
        }
    }

    if constexpr (sizeof(T) == 2) {
        uint4 o;
        o.x = pk2(acc[0], acc[1]); o.y = pk2(acc[2], acc[3]);
        o.z = pk2(acc[4], acc[5]); o.w = pk2(acc[6], acc[7]);
        *(uint4*)(out + obase) = o;
    } else {
        float4 o0; o0.x = acc[0]; o0.y = acc[1]; o0.z = acc[2]; o0.w = acc[3];
        *(float4*)(out + obase) = o0;
    }
}

// ---- LayerNorm over D=256, one block per token, bf16 out ----
__global__ __launch_bounds__(256) void ln_kernel(
    const float* __restrict__ x, const float* __restrict__ g,
    const float* __restrict__ b, bf16* __restrict__ out)
{
    const int t = blockIdx.x;
    const int c = threadIdx.x;
    float v = x[(size_t)t*DD + c];
    __shared__ float s1[256], s2[256];
    s1[c] = v; s2[c] = v*v;
    __syncthreads();
    for (int off = 128; off > 0; off >>= 1) {
        if (c < off) { s1[c] += s1[c+off]; s2[c] += s2[c+off]; }
        __syncthreads();
    }
    float mu  = s1[0] * (1.0f/DD);
    float var = s2[0] * (1.0f/DD) - mu*mu;
    float inv = rsqrtf(var + 1e-6f);
    out[(size_t)t*DD + c] = __float2bfloat16((v - mu) * inv * g[c] + b[c]);
}

// ---- MFMA GEMM: 64x64 tile, 4 waves, 16x16x32 bf16 ----
template<int EPI>
__global__ __launch_bounds__(256) void mgemm_kernel(
    const bf16* __restrict__ A, const float* __restrict__ Wt, int ldw,
    const float* __restrict__ bias, float bs,
    const float* __restrict__ residF, float* accF, bf16* outB, float* outF,
    int M, int N, int K, float scale)
{
    __shared__ unsigned short As[64*40];
    __shared__ unsigned short Bs[64*40];
    const int tid  = threadIdx.x;
    const int wave = tid >> 6;
    const int lane = tid & 63;
    const int quad = lane >> 4;
    const int l15  = lane & 15;
    const int row0 = blockIdx.y * 64;
    const int col0 = blockIdx.x * 64;

    f32x4 acc[4];
    #pragma unroll
    for (int j = 0; j < 4; j++) acc[j] = (f32x4){0.f, 0.f, 0.f, 0.f};

    const int r  = tid >> 2;
    const int cc = tid & 3;

    for (int k0 = 0; k0 < K; k0 += 32) {
        {
            const uint4* src = (const uint4*)(A + (size_t)(row0 + r) * K + k0 + cc*8);
            *(uint4*)(&As[r*40 + cc*8]) = *src;
        }
        {
            const float* s = Wt + (size_t)(col0 + r) * ldw + k0 + cc*8;
            float4 f0 = *(const float4*)(s);
            float4 f1 = *(const float4*)(s + 4);
            uint4 v;
            v.x = pk2(f0.x, f0.y); v.y = pk2(f0.z, f0.w);
            v.z = pk2(f1.x, f1.y); v.w = pk2(f1.z, f1.w);
            *(uint4*)(&Bs[r*40 + cc*8]) = v;
        }
        __syncthreads();
        short8 af = *(const short8*)(&As[(wave*16 + l15)*40 + quad*8]);
        #pragma unroll
        for (int j = 0; j < 4; j++) {
            short8 bf_ = *(const short8*)(&Bs[(j*16 + l15)*40 + quad*8]);
            acc[j] = __builtin_amdgcn_mfma_f32_16x16x32_bf16(af, bf_, acc[j], 0, 0, 0);
        }
        __syncthreads();
    }

    #pragma unroll
    for (int j = 0; j < 4; j++) {
        const int n = col0 + 16*j + l15;
        const float bval = bias[n] * bs;
        #pragma unroll
        for (int reg = 0; reg < 4; reg++) {
            const int m = row0 + wave*16 + quad*4 + reg;
            float y = (acc[j][reg] + bval) * scale;
            size_t o = (size_t)m * N + n;
            if (EPI == 0)      { outB[o] = __float2bfloat16(y); }
            else if (EPI == 1) { y = 0.5f*y*(1.0f + erff(y*0.70710678118654752f)); outB[o] = __float2bfloat16(y); }
            else if (EPI == 2) { accF[o] = residF[o] + y; }
            else if (EPI == 4) { accF[o] += y; }
            else if (EPI == 5) { outF[o] = accF[o] + y; }
        }
    }
}

// ---- RoPE (in place, q and k, bf16) ----
__global__ __launch_bounds__(256) void rope_kernel(bf16* __restrict__ q, bf16* __restrict__ k)
{
    int id = blockIdx.x * 256 + threadIdx.x;
    int t  = id >> 7;
    int r  = id & 127;
    int nh = r >> 4;
    int i  = r & 15;
    int idx = t % (HH * WWD);
    float ang = powf(10000.0f, -(float)i * (1.0f/15.0f));
    float ph  = (float)idx * ang;
    float s = sinf(ph), cn = cosf(ph);
    size_t base = (size_t)t*DD + nh*KDIM + 2*i;
    float q0 = toF(q[base]), q1 = toF(q[base+1]);
    q[base]   = __float2bfloat16(q0*cn - q1*s);
    q[base+1] = __float2bfloat16(q1*cn + q0*s);
    float k0 = toF(k[base]), k1 = toF(k[base+1]);
    k[base]   = __float2bfloat16(k0*cn - k1*s);
    k[base+1] = __float2bfloat16(k1*cn + k0*s);
}

// ---- MFMA decomposed attention. One block per (b, nh, line).
// ROW mode (COLM=0): line = h, attend over w (stride DD);  out = vw, plain write.
// COL mode (COLM=1): line = w, attend over h (stride W*D); out = scrambled + lepe.
template<bool COLM>
__global__ __launch_bounds__(256) void attn_mfma_kernel(
    const bf16* __restrict__ q, const bf16* __restrict__ k,
    const bf16* __restrict__ v, const bf16* __restrict__ lepe,
    bf16* __restrict__ outp)
{
    __shared__ unsigned short Qb[64*40];   // Q[j][d]   row-major, pad 40
    __shared__ unsigned short Kb[64*40];   // K[j][d]   row-major
    __shared__ unsigned short Vt[32*80];   // V^T[d][j] (j padded to 64, stride 80)
    __shared__ float S[64*57];             // scores / probabilities
    __shared__ unsigned short Pb[64*72];   // P bf16, k-padded to 64

    const int bid  = blockIdx.x;
    const int line = bid % 56;
    const int nh   = (bid / 56) % NHEAD;
    const int b    = bid / (56 * NHEAD);
    const int tid  = threadIdx.x;
    const int wid  = tid >> 6;
    const int lane = tid & 63;
    const int quad = lane >> 4;
    const int l15  = lane & 15;

    const size_t rstr = COLM ? (size_t)WWD * DD : (size_t)DD;
    const size_t base = COLM ? (((size_t)b*HH*WWD + line) * DD + nh*KDIM)
                             : (((size_t)(b*HH + line) * WWD) * DD + nh*KDIM);

    // ---- stage Q, K (row-major) and V transposed; zero pads ----
    {
        const int r  = tid >> 2;      // 0..63
        const int cc = tid & 3;       // 16B chunk of the 32-elem row
        uint4 zero = {0,0,0,0};
        if (r < 56) {
            size_t g = base + (size_t)r * rstr + cc*8;
            *(uint4*)(&Qb[r*40 + cc*8]) = *(const uint4*)(q + g);
            *(uint4*)(&Kb[r*40 + cc*8]) = *(const uint4*)(k + g);
        } else {
            *(uint4*)(&Qb[r*40 + cc*8]) = zero;
            *(uint4*)(&Kb[r*40 + cc*8]) = zero;
        }
        for (int t = tid; t < 56*32; t += 256) {
            int j = t >> 5, d = t & 31;
            union { bf16 b_; unsigned short u; } cv;
            cv.b_ = v[base + (size_t)j * rstr + d];
            Vt[d*80 + j] = cv.u;
        }
        { // zero pad columns j = 56..63 (NaN-safety for the PV k-pad)
            int j = 56 + (tid >> 5), d = tid & 31;
            Vt[d*80 + j] = 0;
        }
    }
    __syncthreads();

    // ---- QK^T: wave wid owns row-tile wid; 4 col tiles ----
    {
        short8 af = *(const short8*)(&Qb[(wid*16 + l15)*40 + quad*8]);
        #pragma unroll
        for (int j = 0; j < 4; j++) {
            short8 bfm = *(const short8*)(&Kb[(j*16 + l15)*40 + quad*8]);
            f32x4 acc = {0.f,0.f,0.f,0.f};
            acc = __builtin_amdgcn_mfma_f32_16x16x32_bf16(af, bfm, acc, 0, 0, 0);
            #pragma unroll
            for (int reg = 0; reg < 4; reg++)
                S[(wid*16 + quad*4 + reg)*57 + j*16 + l15] = acc[reg];
        }
    }
    __syncthreads();

    // ---- masked softmax over j<56, rows i<56 (one lane per row) ----
    if (tid < 56) {
        float mx = -1e30f;
        for (int j = 0; j < 56; j++) mx = fmaxf(mx, S[tid*57 + j]);
        float sum = 0.f;
        for (int j = 0; j < 56; j++) { float e = expf(S[tid*57+j] - mx); S[tid*57+j] = e; sum += e; }
        float inv = 1.0f / sum;
        for (int j = 0; j < 56; j++) S[tid*57+j] *= inv;
    }
    __syncthreads();

    // ---- P -> bf16 (A-operand layout source), zero the pads ----
    for (int t = tid; t < 64*64; t += 256) {
        int m = t >> 6, n = t & 63;
        float val = (m < 56 && n < 56) ? S[m*57 + n] : 0.f;
        Pb[m*72 + n] = f2bu(val);
    }
    __syncthreads();

    // ---- PV: O[m][d] = sum_j P[m][j] V[j][d]; 2 n-tiles, 2 k-chunks ----
    {
        f32x4 acc[2];
        acc[0] = (f32x4){0.f,0.f,0.f,0.f};
        acc[1] = (f32x4){0.f,0.f,0.f,0.f};
        #pragma unroll
        for (int k0 = 0; k0 < 64; k0 += 32) {
            short8 af = *(const short8*)(&Pb[(wid*16 + l15)*72 + k0 + quad*8]);
            #pragma unroll
            for (int nt = 0; nt < 2; nt++) {
                short8 bfm = *(const short8*)(&Vt[(nt*16 + l15)*80 + k0 + quad*8]);
                acc[nt] = __builtin_amdgcn_mfma_f32_16x16x32_bf16(af, bfm, acc[nt], 0, 0, 0);
            }
        }
        #pragma unroll
        for (int nt = 0; nt < 2; nt++) {
            #pragma unroll
            for (int reg = 0; reg < 4; reg++) {
                const int m = wid*16 + quad*4 + reg;
                const int d = nt*16 + l15;
                if (m < 56) {
                    float val = acc[nt][reg];
                    if (COLM) {
                        int hp = 7*nh + (m >> 3);
                        int wp = (m & 7)*7 + (line >> 3);
                        int cp = (line & 7)*32 + d;
                        size_t o = ((size_t)(b*HH + hp)*WWD + wp)*DD + cp;
                        outp[o] = __float2bfloat16(val + toF(lepe[o]));
                    } else {
                        outp[base + (size_t)m * rstr + d] = __float2bfloat16(val);
                    }
                }
            }
        }
    }
}

extern "C" void kernel_launch(void* const* d_in, const int* in_sizes, int n_in,
                              void* d_out, int out_size, void* d_ws, size_t ws_size,
                              hipStream_t stream)
{
    const float* x_in   = (const float*)d_in[0];
    const float* cpe_w  = (const float*)d_in[1];
    const float* cpe_b  = (const float*)d_in[2];
    const float* ln1_g  = (const float*)d_in[3];
    const float* ln1_b  = (const float*)d_in[4];
    const float* wq     = (const float*)d_in[5];
    const float* bq     = (const float*)d_in[6];
    const float* wk     = (const float*)d_in[7];
    const float* bk     = (const float*)d_in[8];
    const float* wv     = (const float*)d_in[9];
    const float* bv     = (const float*)d_in[10];
    const float* lepe_w = (const float*)d_in[11];
    const float* lepe_b = (const float*)d_in[12];
    const float* wo     = (const float*)d_in[13];
    const float* bo     = (const float*)d_in[14];
    const float* ln2_g  = (const float*)d_in[15];
    const float* ln2_b  = (const float*)d_in[16];
    const float* fc1_w  = (const float*)d_in[17];
    const float* fc1_b  = (const float*)d_in[18];
    const float* dw_w   = (const float*)d_in[19];
    const float* dw_b   = (const float*)d_in[20];
    const float* fc2_w  = (const float*)d_in[21];
    const float* fc2_b  = (const float*)d_in[22];
    float* out = (float*)d_out;                 // fp32 output (proven)

    const size_t ND = (size_t)NPIX * DD;
    float* X0  = (float*)d_ws;          // fp32 trunk residual 1
    float* ACC = X0 + ND;               // fp32 x1 / fc2 accumulator
    bf16*  B1  = (bf16*)(ACC + ND);     // xn1, then lepe
    bf16*  B2  = B1 + ND;               // q roped, then xn2
    bf16*  B3  = B2 + ND;               // k roped, then h1q
    bf16*  B4  = B3 + ND;               // v, then h2q
    bf16*  VWb   = (bf16*)d_out;        // d_out lo half: vw scratch
    bf16*  ATTNb = VWb + ND;            // d_out hi half: attn scrambled scratch

    dim3 b256(256);
    dim3 gridD(DD/64, NPIX/64);   // (4, 392)

    // 1. CPE: X0 = x + dwconv3x3(x)   [vectorized: 4 px/block, float4 lanes]
    dwconv_vec_kernel<3, float, true><<<NPIX/4, b256, 0, stream>>>(x_in, cpe_w, DD, cpe_b, X0);
    // 2. LN1 -> B1
    ln_kernel<<<NPIX, b256, 0, stream>>>(X0, ln1_g, ln1_b, B1);
    // 3-5. Q,K,V projections (SCALE folded into K)
    mgemm_kernel<0><<<gridD, b256, 0, stream>>>(B1, wq, DD, bq, 1.0f, nullptr, nullptr, B2, nullptr, NPIX, DD, DD, 1.0f);
    mgemm_kernel<0><<<gridD, b256, 0, stream>>>(B1, wk, DD, bk, 1.0f, nullptr, nullptr, B3, nullptr, NPIX, DD, DD, SCALE_K);
    mgemm_kernel<0><<<gridD, b256, 0, stream>>>(B1, wv, DD, bv, 1.0f, nullptr, nullptr, B4, nullptr, NPIX, DD, DD, 1.0f);
    // 6. RoPE in place on q,k
    rope_kernel<<<(NPIX*128)/256, b256, 0, stream>>>(B2, B3);
    // 7. LEPE: B1 = dwconv5x5(v)   [vectorized: 8 px/block, short8 lanes]
    dwconv_vec_kernel<5, bf16, false><<<NPIX/8, b256, 0, stream>>>(B4, lepe_w, DD, lepe_b, B1);
    // 8. Row attention (MFMA): (q,k,v) -> vw
    attn_mfma_kernel<false><<<HB*NHEAD*HH, b256, 0, stream>>>(B2, B3, B4, nullptr, VWb);
    // 9. Column attention (MFMA); scrambled write + lepe -> ATTNb
    attn_mfma_kernel<true><<<HB*NHEAD*WWD, b256, 0, stream>>>(B2, B3, VWb, B1, ATTNb);
    // 10. Output projection + residual: ACC = X0 + ATTNb*wo^T + bo
    mgemm_kernel<2><<<gridD, b256, 0, stream>>>(ATTNb, wo, DD, bo, 1.0f, X0, ACC, nullptr, nullptr, NPIX, DD, DD, 1.0f);
    // 11. LN2 -> B2
    ln_kernel<<<NPIX, b256, 0, stream>>>(ACC, ln2_g, ln2_b, B2);
    // 12-14 x4: FFN in four 256-channel quarters, fc2 accumulated into ACC
    for (int qtr = 0; qtr < 4; qtr++) {
        const int off = qtr * 256;
        mgemm_kernel<1><<<gridD, b256, 0, stream>>>(B2, fc1_w + (size_t)off*DD, DD, fc1_b + off, 1.0f,
                                                    nullptr, nullptr, B3, nullptr, NPIX, 256, DD, 1.0f);
        dwconv_vec_kernel<3, bf16, true><<<NPIX/8, b256, 0, stream>>>(B3, dw_w + off, FFND, dw_b + off, B4);
        if (qtr < 3)
            mgemm_kernel<4><<<gridD, b256, 0, stream>>>(B4, fc2_w + off, FFND, fc2_b, (qtr==0)?1.0f:0.0f,
                                                        nullptr, ACC, nullptr, nullptr, NPIX, DD, 256, 1.0f);
        else
            mgemm_kernel<5><<<gridD, b256, 0, stream>>>(B4, fc2_w + off, FFND, fc2_b, 0.0f,
                                                        nullptr, ACC, nullptr, out, NPIX, DD, 256, 1.0f);
    }
}

// Round 2
// 536.104 us; speedup vs baseline: 1.4097x; 1.0954x over previous
//
#include <hip/hip_runtime.h>
#include <hip/hip_bf16.h>
#include <math.h>

typedef __hip_bfloat16 bf16;

#define HB 8
#define HH 56
#define WWD 56
#define DD 256
#define NHEAD 8
#define KDIM 32
#define FFND 1024
#define NPIX (HB*HH*WWD)             /* 25088 */
#define SCALE_K 0.17677669529663687f /* 32^-0.5 */

typedef __attribute__((ext_vector_type(8))) short short8;   // 8 bf16 (4 VGPRs)
typedef __attribute__((ext_vector_type(4))) float f32x4;

__device__ inline float toF(float x){ return x; }
__device__ inline float toF(bf16 x){ return __bfloat162float(x); }

__device__ inline float bfu_to_f(unsigned short u){
    union { float f; unsigned u32; } cv; cv.u32 = (unsigned)u << 16; return cv.f;
}

__device__ inline unsigned short f2bu(float f){
    union { bf16 b; unsigned short u; } cv; cv.b = __float2bfloat16(f); return cv.u;
}
__device__ inline unsigned pk2(float a, float b){
    return (unsigned)f2bu(a) | ((unsigned)f2bu(b) << 16);
}

// ---- vectorized depthwise conv (SAME, zero pad), optional +input. ----
template<int KS, typename T, bool ADD>
__global__ __launch_bounds__(256) void dwconv_vec_kernel(
    const T* __restrict__ in, const float* __restrict__ wt, int wst,
    const float* __restrict__ bias, T* __restrict__ out)
{
    constexpr int C   = 256;
    constexpr int VEC = (sizeof(T) == 2) ? 8 : 4;
    constexpr int CG  = C / VEC;          // 32 (bf16) or 64 (fp32)
    constexpr int PPB = 256 / CG;         // 8 (bf16) or 4 (fp32)
    constexpr int P   = KS / 2;

    const int tid = threadIdx.x;
    const int cg  = tid % CG;
    const int pl  = tid / CG;
    const int p   = blockIdx.x * PPB + pl;
    const int w   = p % WWD;
    const int h   = (p / WWD) % HH;
    const int b   = p / (WWD * HH);
    const int c0  = cg * VEC;

    float acc[VEC];
    {
        const float4 b0 = *(const float4*)(bias + c0);
        acc[0] = b0.x; acc[1] = b0.y; acc[2] = b0.z; acc[3] = b0.w;
        if constexpr (VEC == 8) {
            const float4 b1 = *(const float4*)(bias + c0 + 4);
            acc[4] = b1.x; acc[5] = b1.y; acc[6] = b1.z; acc[7] = b1.w;
        }
    }

    #pragma unroll
    for (int ky = 0; ky < KS; ky++) {
        const int hh = h + ky - P;
        if (hh < 0 || hh >= HH) continue;
        #pragma unroll
        for (int kx = 0; kx < KS; kx++) {
            const int ww = w + kx - P;
            if (ww < 0 || ww >= WWD) continue;
            const float* wp = wt + (size_t)(ky*KS + kx) * wst + c0;
            float wv[VEC];
            {
                const float4 w0 = *(const float4*)(wp);
                wv[0] = w0.x; wv[1] = w0.y; wv[2] = w0.z; wv[3] = w0.w;
                if constexpr (VEC == 8) {
                    const float4 w1 = *(const float4*)(wp + 4);
                    wv[4] = w1.x; wv[5] = w1.y; wv[6] = w1.z; wv[7] = w1.w;
                }
            }
            const T* src = in + ((size_t)((b*HH + hh)*WWD + ww))*C + c0;
            if constexpr (sizeof(T) == 2) {
                short8 vv = *(const short8*)src;
                #pragma unroll
                for (int j = 0; j < VEC; j++)
                    acc[j] += bfu_to_f((unsigned short)vv[j]) * wv[j];
            } else {
                const float4 f0 = *(const float4*)src;
                acc[0] += f0.x * wv[0]; acc[1] += f0.y * wv[1];
                acc[2] += f0.z * wv[2]; acc[3] += f0.w * wv[3];
            }
        }
    }

    const size_t obase = (size_t)p*C + c0;
    if constexpr (ADD) {
        const T* ip = in + obase;
        if constexpr (sizeof(T) == 2) {
            short8 vv = *(const short8*)ip;
            #pragma unroll
            for (int j = 0; j < VEC; j++) acc[j] += bfu_to_f((unsigned short)vv[j]);
        } else {
            const float4 f0 = *(const float4*)ip;
            acc[0] += f0.x; acc[1] += f0.y; acc[2] += f0.z; acc[3] += f0.w;
        }
    }

    if constexpr (sizeof(T) == 2) {
        uint4 o;
        o.x = pk2(acc[0], acc[1]); o.y = pk2(acc[2], acc[3]);
        o.z = pk2(acc[4], acc[5]); o.w = pk2(acc[6], acc[7]);
        *(uint4*)(out + obase) = o;
    } else {
        float4 o0; o0.x = acc[0]; o0.y = acc[1]; o0.z = acc[2]; o0.w = acc[3];
        *(float4*)(out + obase) = o0;
    }
}

// ---- LayerNorm over D=256: one WAVE per token, shuffle reduce, no barriers ----
__global__ __launch_bounds__(256) void ln_kernel(
    const float* __restrict__ x, const float* __restrict__ g,
    const float* __restrict__ b, bf16* __restrict__ out)
{
    const int wv   = threadIdx.x >> 6;
    const int lane = threadIdx.x & 63;
    const int t    = blockIdx.x * 4 + wv;
    const float4 xv = *(const float4*)(x + (size_t)t*DD + lane*4);
    float s1 = xv.x + xv.y + xv.z + xv.w;
    float s2 = xv.x*xv.x + xv.y*xv.y + xv.z*xv.z + xv.w*xv.w;
    #pragma unroll
    for (int d = 1; d < 64; d <<= 1) {
        s1 += __shfl_xor(s1, d);
        s2 += __shfl_xor(s2, d);
    }
    const float mu  = s1 * (1.0f/DD);
    const float var = s2 * (1.0f/DD) - mu*mu;
    const float inv = rsqrtf(var + 1e-6f);
    const float4 gv = *(const float4*)(g + lane*4);
    const float4 bv = *(const float4*)(b + lane*4);
    uint2 o;
    o.x = pk2((xv.x-mu)*inv*gv.x + bv.x, (xv.y-mu)*inv*gv.y + bv.y);
    o.y = pk2((xv.z-mu)*inv*gv.z + bv.z, (xv.w-mu)*inv*gv.w + bv.w);
    *(uint2*)(out + (size_t)t*DD + lane*4) = o;
}

// ---- MFMA GEMM: 128x128 tile, 4 waves (2x2), acc[4][4], BK=32 ----
// LDS stride 40 ushorts (80B = 5x16B): b128 reads 2-way (free), writes at bank floor.
template<int EPI>
__global__ __launch_bounds__(256) void mgemm128_kernel(
    const bf16* __restrict__ A, const float* __restrict__ Wt, int ldw,
    const float* __restrict__ bias, float bs,
    const float* __restrict__ residF, float* accF, bf16* outB, float* outF,
    int M, int N, int K, float scale)
{
    __shared__ unsigned short As[128*40];
    __shared__ unsigned short Bs[128*40];
    const int tid  = threadIdx.x;
    const int wid  = tid >> 6;
    const int lane = tid & 63;
    const int quad = lane >> 4;
    const int l15  = lane & 15;
    const int wr   = wid >> 1;         // wave row 0..1 (64 rows each)
    const int wc   = wid & 1;          // wave col 0..1 (64 cols each)
    const int row0 = blockIdx.y * 128;
    const int col0 = blockIdx.x * 128;

    f32x4 acc[4][4];
    #pragma unroll
    for (int m = 0; m < 4; m++)
        #pragma unroll
        for (int n = 0; n < 4; n++)
            acc[m][n] = (f32x4){0.f, 0.f, 0.f, 0.f};

    const int r  = tid >> 2;      // 0..63
    const int cc = tid & 3;       // 16B chunk within 32-elem K row

    for (int k0 = 0; k0 < K; k0 += 32) {
        __syncthreads();
        #pragma unroll
        for (int h = 0; h < 2; h++) {
            const int rr = r + h*64;
            const uint4* src = (const uint4*)(A + (size_t)(row0 + rr) * K + k0 + cc*8);
            *(uint4*)(&As[rr*40 + cc*8]) = *src;
        }
        #pragma unroll
        for (int h = 0; h < 2; h++) {
            const int rr = r + h*64;
            const float* s = Wt + (size_t)(col0 + rr) * ldw + k0 + cc*8;
            float4 f0 = *(const float4*)(s);
            float4 f1 = *(const float4*)(s + 4);
            uint4 v;
            v.x = pk2(f0.x, f0.y); v.y = pk2(f0.z, f0.w);
            v.z = pk2(f1.x, f1.y); v.w = pk2(f1.z, f1.w);
            *(uint4*)(&Bs[rr*40 + cc*8]) = v;
        }
        __syncthreads();
        short8 af[4], bfr[4];
        #pragma unroll
        for (int m = 0; m < 4; m++)
            af[m] = *(const short8*)(&As[(wr*64 + m*16 + l15)*40 + quad*8]);
        #pragma unroll
        for (int n = 0; n < 4; n++)
            bfr[n] = *(const short8*)(&Bs[(wc*64 + n*16 + l15)*40 + quad*8]);
        #pragma unroll
        for (int m = 0; m < 4; m++)
            #pragma unroll
            for (int n = 0; n < 4; n++)
                acc[m][n] = __builtin_amdgcn_mfma_f32_16x16x32_bf16(af[m], bfr[n], acc[m][n], 0, 0, 0);
    }

    #pragma unroll
    for (int n = 0; n < 4; n++) {
        const int nn = col0 + wc*64 + n*16 + l15;
        const float bval = bias[nn] * bs;
        #pragma unroll
        for (int m = 0; m < 4; m++) {
            #pragma unroll
            for (int reg = 0; reg < 4; reg++) {
                const int mm = row0 + wr*64 + m*16 + quad*4 + reg;
                float y = (acc[m][n][reg] + bval) * scale;
                size_t o = (size_t)mm * N + nn;
                if (EPI == 0)      { outB[o] = __float2bfloat16(y); }
                else if (EPI == 1) { y = 0.5f*y*(1.0f + erff(y*0.70710678118654752f)); outB[o] = __float2bfloat16(y); }
                else if (EPI == 2) { accF[o] = residF[o] + y; }
                else if (EPI == 4) { accF[o] += y; }
                else if (EPI == 5) { outF[o] = accF[o] + y; }
            }
        }
    }
}

// ---- RoPE (in place, q and k, bf16) ----
__global__ __launch_bounds__(256) void rope_kernel(bf16* __restrict__ q, bf16* __restrict__ k)
{
    int id = blockIdx.x * 256 + threadIdx.x;
    int t  = id >> 7;
    int r  = id & 127;
    int nh = r >> 4;
    int i  = r & 15;
    int idx = t % (HH * WWD);
    float ang = exp2f(-(float)i * 0.88584749196996324f);  /* 10000^(-i/15) */
    float ph  = (float)idx * ang;
    float s = sinf(ph), cn = cosf(ph);
    size_t base = (size_t)t*DD + nh*KDIM + 2*i;
    float q0 = toF(q[base]), q1 = toF(q[base+1]);
    q[base]   = __float2bfloat16(q0*cn - q1*s);
    q[base+1] = __float2bfloat16(q1*cn + q0*s);
    float k0 = toF(k[base]), k1 = toF(k[base+1]);
    k[base]   = __float2bfloat16(k0*cn - k1*s);
    k[base+1] = __float2bfloat16(k1*cn + k0*s);
}

// ---- MFMA decomposed attention, in-register softmax version.
// One block per (b, nh, line). ROW mode: attend over w. COL mode: attend over h,
// scrambled output + lepe.
template<bool COLM>
__global__ __launch_bounds__(256) void attn_mfma_kernel(
    const bf16* __restrict__ q, const bf16* __restrict__ k,
    const bf16* __restrict__ v, const bf16* __restrict__ lepe,
    bf16* __restrict__ outp)
{
    __shared__ unsigned short Qb[64*40];   // Q[j][d] row-major, pad 40
    __shared__ unsigned short Kb[64*40];   // K[j][d] row-major
    __shared__ unsigned short Vt[32*80];   // V^T[d][j] (j padded to 64, stride 80)
    __shared__ unsigned short Pb[64*72];   // P bf16, k-padded to 64

    const int bid  = blockIdx.x;
    const int line = bid % 56;
    const int nh   = (bid / 56) % NHEAD;
    const int b    = bid / (56 * NHEAD);
    const int tid  = threadIdx.x;
    const int wid  = tid >> 6;
    const int lane = tid & 63;
    const int quad = lane >> 4;
    const int l15  = lane & 15;

    const size_t rstr = COLM ? (size_t)WWD * DD : (size_t)DD;
    const size_t base = COLM ? (((size_t)b*HH*WWD + line) * DD + nh*KDIM)
                             : (((size_t)(b*HH + line) * WWD) * DD + nh*KDIM);

    // ---- stage Q, K (row-major, uint4) and V transposed (uint4 + scatter) ----
    {
        const int r  = tid >> 2;      // 0..63
        const int cc = tid & 3;       // 16B chunk of the 32-elem row
        uint4 zero = {0,0,0,0};
        if (r < 56) {
            size_t g = base + (size_t)r * rstr + cc*8;
            *(uint4*)(&Qb[r*40 + cc*8]) = *(const uint4*)(q + g);
            *(uint4*)(&Kb[r*40 + cc*8]) = *(const uint4*)(k + g);
        } else {
            *(uint4*)(&Qb[r*40 + cc*8]) = zero;
            *(uint4*)(&Kb[r*40 + cc*8]) = zero;
        }
        // V: wave wid owns d-chunk wid*8..wid*8+7; lane = source row j.
        // Lanes 56..63 write zeros -> pad columns zeroed automatically.
        uint4 vv = zero;
        if (lane < 56)
            vv = *(const uint4*)(v + base + (size_t)lane * rstr + wid*8);
        const unsigned short* pv = (const unsigned short*)&vv;
        #pragma unroll
        for (int e = 0; e < 8; e++)
            Vt[(wid*8 + e)*80 + lane] = pv[e];
    }
    __syncthreads();

    // ---- QK^T (wave wid owns rows wid*16..+15) + in-register masked softmax ----
    {
        short8 af = *(const short8*)(&Qb[(wid*16 + l15)*40 + quad*8]);
        f32x4 s_[4];
        #pragma unroll
        for (int j = 0; j < 4; j++) {
            short8 bfm = *(const short8*)(&Kb[(j*16 + l15)*40 + quad*8]);
            f32x4 z = {0.f,0.f,0.f,0.f};
            s_[j] = __builtin_amdgcn_mfma_f32_16x16x32_bf16(af, bfm, z, 0, 0, 0);
        }
        // value(row = wid*16 + quad*4 + reg, col = j*16 + l15) = s_[j][reg]
        const bool v3 = (l15 < 8);          // col = 48+l15 valid iff l15 < 8
        float mx[4], sm[4];
        #pragma unroll
        for (int reg = 0; reg < 4; reg++) {
            float m01 = fmaxf(s_[0][reg], s_[1][reg]);
            float m23 = v3 ? fmaxf(s_[2][reg], s_[3][reg]) : s_[2][reg];
            mx[reg] = fmaxf(m01, m23);
        }
        #pragma unroll
        for (int d = 1; d < 16; d <<= 1) {
            #pragma unroll
            for (int reg = 0; reg < 4; reg++)
                mx[reg] = fmaxf(mx[reg], __shfl_xor(mx[reg], d));
        }
        float e_[4][4];
        #pragma unroll
        for (int reg = 0; reg < 4; reg++) sm[reg] = 0.f;
        #pragma unroll
        for (int j = 0; j < 4; j++) {
            #pragma unroll
            for (int reg = 0; reg < 4; reg++) {
                const bool valid = (j < 3) || v3;
                float ex = valid ? expf(s_[j][reg] - mx[reg]) : 0.f;
                e_[j][reg] = ex;
                sm[reg] += ex;
            }
        }
        #pragma unroll
        for (int d = 1; d < 16; d <<= 1) {
            #pragma unroll
            for (int reg = 0; reg < 4; reg++)
                sm[reg] += __shfl_xor(sm[reg], d);
        }
        float inv[4];
        #pragma unroll
        for (int reg = 0; reg < 4; reg++) inv[reg] = 1.0f / sm[reg];
        // write P (bf16) directly; pad cols get 0 (ex=0), pad rows finite garbage (masked later)
        #pragma unroll
        for (int j = 0; j < 4; j++)
            #pragma unroll
            for (int reg = 0; reg < 4; reg++)
                Pb[(wid*16 + quad*4 + reg)*72 + j*16 + l15] = f2bu(e_[j][reg] * inv[reg]);
    }
    __syncthreads();

    // ---- PV: O[m][d] = sum_j P[m][j] V[j][d]; 2 n-tiles, 2 k-chunks ----
    {
        f32x4 acc[2];
        acc[0] = (f32x4){0.f,0.f,0.f,0.f};
        acc[1] = (f32x4){0.f,0.f,0.f,0.f};
        #pragma unroll
        for (int k0 = 0; k0 < 64; k0 += 32) {
            short8 af = *(const short8*)(&Pb[(wid*16 + l15)*72 + k0 + quad*8]);
            #pragma unroll
            for (int nt = 0; nt < 2; nt++) {
                short8 bfm = *(const short8*)(&Vt[(nt*16 + l15)*80 + k0 + quad*8]);
                acc[nt] = __builtin_amdgcn_mfma_f32_16x16x32_bf16(af, bfm, acc[nt], 0, 0, 0);
            }
        }
        #pragma unroll
        for (int nt = 0; nt < 2; nt++) {
            #pragma unroll
            for (int reg = 0; reg < 4; reg++) {
                const int m = wid*16 + quad*4 + reg;
                const int d = nt*16 + l15;
                if (m < 56) {
                    float val = acc[nt][reg];
                    if (COLM) {
                        int hp = 7*nh + (m >> 3);
                        int wp = (m & 7)*7 + (line >> 3);
                        int cp = (line & 7)*32 + d;
                        size_t o = ((size_t)(b*HH + hp)*WWD + wp)*DD + cp;
                        outp[o] = __float2bfloat16(val + toF(lepe[o]));
                    } else {
                        outp[base + (size_t)m * rstr + d] = __float2bfloat16(val);
                    }
                }
            }
        }
    }
}

extern "C" void kernel_launch(void* const* d_in, const int* in_sizes, int n_in,
                              void* d_out, int out_size, void* d_ws, size_t ws_size,
                              hipStream_t stream)
{
    const float* x_in   = (const float*)d_in[0];
    const float* cpe_w  = (const float*)d_in[1];
    const float* cpe_b  = (const float*)d_in[2];
    const float* ln1_g  = (const float*)d_in[3];
    const float* ln1_b  = (const float*)d_in[4];
    const float* wq     = (const float*)d_in[5];
    const float* bq     = (const float*)d_in[6];
    const float* wk     = (const float*)d_in[7];
    const float* bk     = (const float*)d_in[8];
    const float* wv     = (const float*)d_in[9];
    const float* bv     = (const float*)d_in[10];
    const float* lepe_w = (const float*)d_in[11];
    const float* lepe_b = (const float*)d_in[12];
    const float* wo     = (const float*)d_in[13];
    const float* bo     = (const float*)d_in[14];
    const float* ln2_g  = (const float*)d_in[15];
    const float* ln2_b  = (const float*)d_in[16];
    const float* fc1_w  = (const float*)d_in[17];
    const float* fc1_b  = (const float*)d_in[18];
    const float* dw_w   = (const float*)d_in[19];
    const float* dw_b   = (const float*)d_in[20];
    const float* fc2_w  = (const float*)d_in[21];
    const float* fc2_b  = (const float*)d_in[22];
    float* out = (float*)d_out;                 // fp32 output

    const size_t ND = (size_t)NPIX * DD;
    float* X0  = (float*)d_ws;          // fp32 trunk residual 1
    float* ACC = X0 + ND;               // fp32 x1 / fc2 accumulator
    bf16*  B1  = (bf16*)(ACC + ND);     // xn1, then lepe
    bf16*  B2  = B1 + ND;               // q roped, then xn2
    bf16*  B3  = B2 + ND;               // k roped, then h1q
    bf16*  B4  = B3 + ND;               // v, then h2q
    bf16*  VWb   = (bf16*)d_out;        // d_out lo half: vw scratch
    bf16*  ATTNb = VWb + ND;            // d_out hi half: attn scrambled scratch

    dim3 b256(256);
    dim3 gridG(DD/128, NPIX/128);   // (2, 196)

    // 1. CPE: X0 = x + dwconv3x3(x)
    dwconv_vec_kernel<3, float, true><<<NPIX/4, b256, 0, stream>>>(x_in, cpe_w, DD, cpe_b, X0);
    // 2. LN1 -> B1
    ln_kernel<<<NPIX/4, b256, 0, stream>>>(X0, ln1_g, ln1_b, B1);
    // 3-5. Q,K,V projections (SCALE folded into K)
    mgemm128_kernel<0><<<gridG, b256, 0, stream>>>(B1, wq, DD, bq, 1.0f, nullptr, nullptr, B2, nullptr, NPIX, DD, DD, 1.0f);
    mgemm128_kernel<0><<<gridG, b256, 0, stream>>>(B1, wk, DD, bk, 1.0f, nullptr, nullptr, B3, nullptr, NPIX, DD, DD, SCALE_K);
    mgemm128_kernel<0><<<gridG, b256, 0, stream>>>(B1, wv, DD, bv, 1.0f, nullptr, nullptr, B4, nullptr, NPIX, DD, DD, 1.0f);
    // 6. RoPE in place on q,k
    rope_kernel<<<(NPIX*128)/256, b256, 0, stream>>>(B2, B3);
    // 7. LEPE: B1 = dwconv5x5(v)
    dwconv_vec_kernel<5, bf16, false><<<NPIX/8, b256, 0, stream>>>(B4, lepe_w, DD, lepe_b, B1);
    // 8. Row attention (MFMA): (q,k,v) -> vw
    attn_mfma_kernel<false><<<HB*NHEAD*HH, b256, 0, stream>>>(B2, B3, B4, nullptr, VWb);
    // 9. Column attention (MFMA); scrambled write + lepe -> ATTNb
    attn_mfma_kernel<true><<<HB*NHEAD*WWD, b256, 0, stream>>>(B2, B3, VWb, B1, ATTNb);
    // 10. Output projection + residual: ACC = X0 + ATTNb*wo^T + bo
    mgemm128_kernel<2><<<gridG, b256, 0, stream>>>(ATTNb, wo, DD, bo, 1.0f, X0, ACC, nullptr, nullptr, NPIX, DD, DD, 1.0f);
    // 11. LN2 -> B2
    ln_kernel<<<NPIX/4, b256, 0, stream>>>(ACC, ln2_g, ln2_b, B2);
    // 12-14 x4: FFN in four 256-channel quarters, fc2 accumulated into ACC
    for (int qtr = 0; qtr < 4; qtr++) {
        const int off = qtr * 256;
        mgemm128_kernel<1><<<gridG, b256, 0, stream>>>(B2, fc1_w + (size_t)off*DD, DD, fc1_b + off, 1.0f,
                                                       nullptr, nullptr, B3, nullptr, NPIX, 256, DD, 1.0f);
        dwconv_vec_kernel<3, bf16, true><<<NPIX/8, b256, 0, stream>>>(B3, dw_w + off, FFND, dw_b + off, B4);
        if (qtr < 3)
            mgemm128_kernel<4><<<gridG, b256, 0, stream>>>(B4, fc2_w + off, FFND, fc2_b, (qtr==0)?1.0f:0.0f,
                                                           nullptr, ACC, nullptr, nullptr, NPIX, DD, 256, 1.0f);
        else
            mgemm128_kernel<5><<<gridG, b256, 0, stream>>>(B4, fc2_w + off, FFND, fc2_b, 0.0f,
                                                           nullptr, ACC, nullptr, out, NPIX, DD, 256, 1.0f);
    }
}